// Round 8
// baseline (167.353 us; speedup 1.0000x reference)
//
#include <hip/hip_runtime.h>
#include <hip/hip_bf16.h>
#include <stdint.h>

typedef unsigned short u16;
typedef signed char i8;

#define D_INNER 2048
#define D_OUTER 2048
#define MROWS   8192                 // B*S = 2*4096
#define W_ELEMS (D_OUTER * D_INNER)  // 4194304
#define NPART   1024                 // absmean partial blocks

// ---- gemm geometry: 256x128 tile, BK=128 i8, SINGLE 48KB buffer, 2 blocks/CU ----
#define BM 256
#define BN 128
#define BK 128
#define NKT (D_INNER / BK)           // 16 K-tiles
#define LDS_TOTAL 49152              // A 32KB + B 16KB, single-buffered

typedef __attribute__((ext_vector_type(4))) float f32x4;
typedef __attribute__((ext_vector_type(4))) int   i32x4;
typedef __attribute__((ext_vector_type(16))) int  i32x16;

// ------- 1) prep (FROZEN from R5/R6): RMSNorm one wave/row + |w| partials -------
__global__ __launch_bounds__(256) void prep_kernel(const float* __restrict__ x,
                            const float* __restrict__ g,
                            const float* __restrict__ w,
                            i8* __restrict__ xn, float* __restrict__ srow,
                            float* __restrict__ partials) {
  int t = threadIdx.x;
  int lane = t & 63, wvi = t >> 6;

  if (blockIdx.x >= MROWS / 4) {
    __shared__ float red[4];
    int p = blockIdx.x - MROWS / 4;
    int base = p * 1024;
    float s = 0.f;
#pragma unroll
    for (int r = 0; r < 4; ++r) {
      f32x4 v = ((const f32x4*)w)[base + r * 256 + t];
      s += fabsf(v[0]) + fabsf(v[1]) + fabsf(v[2]) + fabsf(v[3]);
    }
    for (int off = 32; off; off >>= 1) s += __shfl_down(s, off, 64);
    if (lane == 0) red[wvi] = s;
    __syncthreads();
    if (t == 0) partials[p] = red[0] + red[1] + red[2] + red[3];
    return;
  }

  int row = blockIdx.x * 4 + wvi;
  const f32x4* xr = (const f32x4*)(x + (size_t)row * D_INNER);
  const f32x4* gr = (const f32x4*)g;
  i8* xo = xn + (size_t)row * D_INNER;

  f32x4 v[8], gv[8];
#pragma unroll
  for (int r = 0; r < 8; ++r) {
    v[r]  = __builtin_nontemporal_load(&xr[lane + r * 64]);
    gv[r] = gr[lane + r * 64];
  }
  float s = 0.f, m = 0.f;
#pragma unroll
  for (int r = 0; r < 8; ++r) {
    s += v[r][0]*v[r][0] + v[r][1]*v[r][1] + v[r][2]*v[r][2] + v[r][3]*v[r][3];
    m = fmaxf(m, fmaxf(fmaxf(fabsf(v[r][0]*gv[r][0]), fabsf(v[r][1]*gv[r][1])),
                       fmaxf(fabsf(v[r][2]*gv[r][2]), fabsf(v[r][3]*gv[r][3]))));
  }
#pragma unroll
  for (int off = 32; off; off >>= 1) {
    s += __shfl_xor(s, off, 64);
    m = fmaxf(m, __shfl_xor(m, off, 64));
  }
  float invr = 1.0f / sqrtf(s * (1.0f / (float)D_INNER) + 1e-6f);
  float amax = fmaxf(m * invr, 1e-12f);
  float step = amax * (1.0f / 127.0f);
  float qs   = 127.0f / amax;
  if (lane == 0) srow[row] = step;

#pragma unroll
  for (int r = 0; r < 8; ++r) {
    char4 q;
    float qv;
    qv = fminf(127.f, fmaxf(-127.f, rintf(v[r][0]*invr*gv[r][0]*qs))); q.x = (i8)(int)qv;
    qv = fminf(127.f, fmaxf(-127.f, rintf(v[r][1]*invr*gv[r][1]*qs))); q.y = (i8)(int)qv;
    qv = fminf(127.f, fmaxf(-127.f, rintf(v[r][2]*invr*gv[r][2]*qs))); q.z = (i8)(int)qv;
    qv = fminf(127.f, fmaxf(-127.f, rintf(v[r][3]*invr*gv[r][3]*qs))); q.w = (i8)(int)qv;
    ((char4*)xo)[lane + r * 64] = q;
  }
}

// ------- 2) ternary quantize (FROZEN) -------
__global__ __launch_bounds__(256) void quant_kernel(const float* __restrict__ w,
                             const float* __restrict__ partials,
                             float* __restrict__ gamma_out, i8* __restrict__ wq) {
  f32x4 pv = ((const f32x4*)partials)[threadIdx.x];
  double d = (double)pv[0] + (double)pv[1] + (double)pv[2] + (double)pv[3];
  for (int off = 32; off; off >>= 1) d += __shfl_down(d, off, 64);
  __shared__ double red[4];
  int lane = threadIdx.x & 63, wvi = threadIdx.x >> 6;
  if (lane == 0) red[wvi] = d;
  __syncthreads();
  double total = red[0] + red[1] + red[2] + red[3];
  float gamma = (float)(total * (1.0 / (double)W_ELEMS));
  float inv = 1.0f / (gamma + 1e-8f);
  if (blockIdx.x == 0 && threadIdx.x == 0) *gamma_out = gamma;

  int tid = blockIdx.x * blockDim.x + threadIdx.x;
  int stride = gridDim.x * blockDim.x;
  for (int i = tid; i < W_ELEMS / 4; i += stride) {
    f32x4 v = ((const f32x4*)w)[i];
    char4 q;
    q.x = (i8)(int)fminf(1.f, fmaxf(-1.f, rintf(v[0] * inv)));
    q.y = (i8)(int)fminf(1.f, fmaxf(-1.f, rintf(v[1] * inv)));
    q.z = (i8)(int)fminf(1.f, fmaxf(-1.f, rintf(v[2] * inv)));
    q.w = (i8)(int)fminf(1.f, fmaxf(-1.f, rintf(v[3] * inv)));
    ((char4*)wq)[i] = q;
  }
}

// ------- 3) i8 GEMM: 256x128 tile, single buffer, 2 blocks/CU -------
// The variable never moved in R0-R7: occupancy (always 1 block/CU; R6 = 1
// wave/SIMD, OccupancyPercent 9.2 -> all stalls exposed). R8 = R6's verified
// compute body on a 256x128 tile: 512 blocks -> 2 blocks/CU, 2 waves/SIMD.
// Single 48KB buffer (A 32KB + B 16KB); the drain loop's stage+wait window
// is covered by the OTHER resident block's MFMA (m114 co-scheduling), not by
// same-block schedule tricks (R1-R7's repeated failure). Addressing formulas
// bit-identical to R6 (A unchanged; B = 4 staging rounds, nj<2).
#define GLDS(SRC, DST) __builtin_amdgcn_global_load_lds( \
    (const __attribute__((address_space(1))) void*)(SRC), \
    (__attribute__((address_space(3))) void*)(DST), 16, 0, 0)
#define WAITVM(N) asm volatile("s_waitcnt vmcnt(" #N ")")
#define BAR()     __builtin_amdgcn_s_barrier()
#define FENCE()   __builtin_amdgcn_sched_barrier(0)

__global__ __launch_bounds__(256, 2) void gemm_bt(const i8* __restrict__ A,
                                                  const i8* __restrict__ Bw,
                                                  const float* __restrict__ gamma_p,
                                                  const float* __restrict__ srow,
                                                  float* __restrict__ C) {
  extern __shared__ i8 lds[];   // A at 0 (32KB), B at 32768 (16KB)

  // XCD swizzle over 512 blocks: xcd owns mb in [xcd*4, xcd*4+4) x all 16 nb
  // (A panel 2MB L2-resident; B 4MB streams/caches).
  int f   = blockIdx.y * 8 + blockIdx.x;   // 0..511, x-fastest
  int xcd = f & 7;
  int gg  = f >> 3;                        // 0..63
  int orig = xcd * 64 + gg;
  int nb  = orig & 15;                     // 0..15
  int mb  = orig >> 4;                     // 0..31
  int bm0 = mb * BM;
  int bn0 = nb * BN;

  int tid  = threadIdx.x;
  int lane = tid & 63;
  int wv   = tid >> 6;          // 0..3
  int wr   = wv >> 1;           // 0..1 -> rows wr*128
  int wc   = wv & 1;            // 0..1 -> cols wc*64
  int l31  = lane & 31;
  int hi   = lane >> 5;

  const i8* Ag = A  + (size_t)bm0 * D_INNER;
  const i8* Bg = Bw + (size_t)bn0 * D_INNER;

  // staging decode (verified R3/R6): round rr covers rows rr*32+(tid>>3);
  // src chunk XOR'd by row&7 (== (tid>>3)&7); dst linear rr*4096 + tid*16.
  size_t srcx = (size_t)(tid >> 3) * D_INNER + (((tid & 7) ^ ((tid >> 3) & 7)) << 4);

  // read addressing (verified)
  int rdA = (wr * 128 + l31) * BK;            // + mi*4096 + swz[ks]
  int rdB = 32768 + (wc * 64 + l31) * BK;     // + nj*4096 + swz[ks]
  int swz[4];
#pragma unroll
  for (int ks = 0; ks < 4; ++ks)
    swz[ks] = (((ks << 1) | hi) ^ (l31 & 7)) << 4;

  i32x16 acc[4][2] = {};

#define STAGE(T_) do { \
    _Pragma("unroll") for (int rr = 0; rr < 8; ++rr) \
      GLDS(Ag + srcx + (size_t)rr * (32 * D_INNER) + (size_t)(T_) * BK, \
           lds + rr * 4096 + tid * 16); \
    _Pragma("unroll") for (int rr = 0; rr < 4; ++rr) \
      GLDS(Bg + srcx + (size_t)rr * (32 * D_INNER) + (size_t)(T_) * BK, \
           lds + 32768 + rr * 4096 + tid * 16); \
  } while (0)

#define MFMA8(P_, AF) do { \
    __builtin_amdgcn_s_setprio(1); \
    _Pragma("unroll") for (int ks = 0; ks < 4; ++ks) \
      _Pragma("unroll") for (int nj = 0; nj < 2; ++nj) \
        acc[P_][nj] = __builtin_amdgcn_mfma_i32_32x32x32_i8( \
            AF[ks], bf_[ks][nj], acc[P_][nj], 0, 0, 0); \
    __builtin_amdgcn_s_setprio(0); \
  } while (0)

#define COMPUTE() do { \
    i32x4 bf_[4][2]; \
    _Pragma("unroll") for (int ks = 0; ks < 4; ++ks) \
      _Pragma("unroll") for (int nj = 0; nj < 2; ++nj) \
        bf_[ks][nj] = *(const i32x4*)(lds + rdB + nj * 4096 + swz[ks]); \
    _Pragma("unroll") for (int mi = 0; mi < 4; ++mi) { \
      i32x4 af_[4]; \
      _Pragma("unroll") for (int ks = 0; ks < 4; ++ks) \
        af_[ks] = *(const i32x4*)(lds + rdA + mi * 4096 + swz[ks]); \
      MFMA8(mi, af_); \
    } \
  } while (0)

  STAGE(0);

  for (int t = 0; t < NKT; ++t) {
    WAITVM(0);                 // tile t's 12 loads landed (this wave)
    FENCE();
    BAR();                     // publish tile t across waves
    FENCE();
    COMPUTE();
    FENCE();
    if (t < NKT - 1) {
      BAR();                   // all waves done reading the buffer
      FENCE();
      STAGE(t + 1);            // overwrite; other block computes meanwhile
    }
  }

  // epilogue: C/D 32x32 layout: col = lane&31, row = (reg&3) + 8*(reg>>2) + 4*hi
  float gamma = *gamma_p;
#pragma unroll
  for (int mi = 0; mi < 4; ++mi) {
    int rbase = bm0 + wr * 128 + mi * 32 + hi * 4;
    f32x4 sg[4];
#pragma unroll
    for (int q = 0; q < 4; ++q) {
      f32x4 sv = *(const f32x4*)(srow + rbase + q * 8);
      sg[q] = sv * gamma;
    }
#pragma unroll
    for (int nj = 0; nj < 2; ++nj) {
      int colb = bn0 + wc * 64 + nj * 32 + l31;
      i32x16 v = acc[mi][nj];
      float* cp = C + (size_t)rbase * D_OUTER + colb;
#pragma unroll
      for (int q = 0; q < 4; ++q)
#pragma unroll
        for (int rr = 0; rr < 4; ++rr)
          cp[(size_t)(q * 8 + rr) * D_OUTER] = (float)v[q * 4 + rr] * sg[q][rr];
    }
  }
}

extern "C" void kernel_launch(void* const* d_in, const int* in_sizes, int n_in,
                              void* d_out, int out_size, void* d_ws, size_t ws_size,
                              hipStream_t stream) {
  const float* x = (const float*)d_in[0];   // [2,4096,2048]
  const float* w = (const float*)d_in[1];   // [2048,2048]
  const float* g = (const float*)d_in[2];   // [2048]
  float* out = (float*)d_out;               // [2,4096,2048] fp32

  float* gamma_p  = (float*)d_ws;                                  // 1 float
  float* partials = (float*)((char*)d_ws + 64);                    // 1024 floats
  float* srow     = (float*)((char*)d_ws + 8192);                  // 8192 floats
  i8* xn = (i8*)((char*)d_ws + 8192 + 32768);                      // 16 MB
  i8* wq = (i8*)((char*)d_ws + 8192 + 32768 + (size_t)MROWS * D_INNER);  // 4 MB

  static bool attr_set = false;
  if (!attr_set) {
    (void)hipFuncSetAttribute(reinterpret_cast<const void*>(&gemm_bt),
                              hipFuncAttributeMaxDynamicSharedMemorySize, LDS_TOTAL);
    attr_set = true;
  }

  prep_kernel<<<MROWS / 4 + NPART, 256, 0, stream>>>(x, g, w, xn, srow, partials);
  quant_kernel<<<2048, 256, 0, stream>>>(w, partials, gamma_p, wq);
  gemm_bt<<<dim3(8, 64), 256, LDS_TOTAL, stream>>>(xn, wq, gamma_p, srow, out);
}

// Round 9
// 166.011 us; speedup vs baseline: 1.0081x; 1.0081x over previous
//
#include <hip/hip_runtime.h>
#include <hip/hip_bf16.h>
#include <stdint.h>

typedef unsigned short u16;
typedef signed char i8;

#define D_INNER 2048
#define D_OUTER 2048
#define MROWS   8192                 // B*S = 2*4096
#define W_ELEMS (D_OUTER * D_INNER)  // 4194304
#define NPART   1024                 // absmean partial blocks

// ---- gemm geometry: 256x256 tile, BK=128 i8, 4 waves x (128x128) out ----
#define BM 256
#define BN 256
#define BK 128
#define NKT (D_INNER / BK)           // 16 K-tiles
#define SLOT_BYTES 65536             // A 32KB + B 32KB
#define LDS_TOTAL  131072            // 2 slots

typedef __attribute__((ext_vector_type(4))) float f32x4;
typedef __attribute__((ext_vector_type(4))) int   i32x4;
typedef __attribute__((ext_vector_type(16))) int  i32x16;

// ------- 1) prep (FROZEN): RMSNorm one wave/row + |w| partials -------
__global__ __launch_bounds__(256) void prep_kernel(const float* __restrict__ x,
                            const float* __restrict__ g,
                            const float* __restrict__ w,
                            i8* __restrict__ xn, float* __restrict__ srow,
                            float* __restrict__ partials) {
  int t = threadIdx.x;
  int lane = t & 63, wvi = t >> 6;

  if (blockIdx.x >= MROWS / 4) {
    __shared__ float red[4];
    int p = blockIdx.x - MROWS / 4;
    int base = p * 1024;
    float s = 0.f;
#pragma unroll
    for (int r = 0; r < 4; ++r) {
      f32x4 v = ((const f32x4*)w)[base + r * 256 + t];
      s += fabsf(v[0]) + fabsf(v[1]) + fabsf(v[2]) + fabsf(v[3]);
    }
    for (int off = 32; off; off >>= 1) s += __shfl_down(s, off, 64);
    if (lane == 0) red[wvi] = s;
    __syncthreads();
    if (t == 0) partials[p] = red[0] + red[1] + red[2] + red[3];
    return;
  }

  int row = blockIdx.x * 4 + wvi;
  const f32x4* xr = (const f32x4*)(x + (size_t)row * D_INNER);
  const f32x4* gr = (const f32x4*)g;
  i8* xo = xn + (size_t)row * D_INNER;

  f32x4 v[8], gv[8];
#pragma unroll
  for (int r = 0; r < 8; ++r) {
    v[r]  = __builtin_nontemporal_load(&xr[lane + r * 64]);
    gv[r] = gr[lane + r * 64];
  }
  float s = 0.f, m = 0.f;
#pragma unroll
  for (int r = 0; r < 8; ++r) {
    s += v[r][0]*v[r][0] + v[r][1]*v[r][1] + v[r][2]*v[r][2] + v[r][3]*v[r][3];
    m = fmaxf(m, fmaxf(fmaxf(fabsf(v[r][0]*gv[r][0]), fabsf(v[r][1]*gv[r][1])),
                       fmaxf(fabsf(v[r][2]*gv[r][2]), fabsf(v[r][3]*gv[r][3]))));
  }
#pragma unroll
  for (int off = 32; off; off >>= 1) {
    s += __shfl_xor(s, off, 64);
    m = fmaxf(m, __shfl_xor(m, off, 64));
  }
  float invr = 1.0f / sqrtf(s * (1.0f / (float)D_INNER) + 1e-6f);
  float amax = fmaxf(m * invr, 1e-12f);
  float step = amax * (1.0f / 127.0f);
  float qs   = 127.0f / amax;
  if (lane == 0) srow[row] = step;

#pragma unroll
  for (int r = 0; r < 8; ++r) {
    char4 q;
    float qv;
    qv = fminf(127.f, fmaxf(-127.f, rintf(v[r][0]*invr*gv[r][0]*qs))); q.x = (i8)(int)qv;
    qv = fminf(127.f, fmaxf(-127.f, rintf(v[r][1]*invr*gv[r][1]*qs))); q.y = (i8)(int)qv;
    qv = fminf(127.f, fmaxf(-127.f, rintf(v[r][2]*invr*gv[r][2]*qs))); q.z = (i8)(int)qv;
    qv = fminf(127.f, fmaxf(-127.f, rintf(v[r][3]*invr*gv[r][3]*qs))); q.w = (i8)(int)qv;
    ((char4*)xo)[lane + r * 64] = q;
  }
}

// ------- 2) ternary quantize (FROZEN) -------
__global__ __launch_bounds__(256) void quant_kernel(const float* __restrict__ w,
                             const float* __restrict__ partials,
                             float* __restrict__ gamma_out, i8* __restrict__ wq) {
  f32x4 pv = ((const f32x4*)partials)[threadIdx.x];
  double d = (double)pv[0] + (double)pv[1] + (double)pv[2] + (double)pv[3];
  for (int off = 32; off; off >>= 1) d += __shfl_down(d, off, 64);
  __shared__ double red[4];
  int lane = threadIdx.x & 63, wvi = threadIdx.x >> 6;
  if (lane == 0) red[wvi] = d;
  __syncthreads();
  double total = red[0] + red[1] + red[2] + red[3];
  float gamma = (float)(total * (1.0 / (double)W_ELEMS));
  float inv = 1.0f / (gamma + 1e-8f);
  if (blockIdx.x == 0 && threadIdx.x == 0) *gamma_out = gamma;

  int tid = blockIdx.x * blockDim.x + threadIdx.x;
  int stride = gridDim.x * blockDim.x;
  for (int i = tid; i < W_ELEMS / 4; i += stride) {
    f32x4 v = ((const f32x4*)w)[i];
    char4 q;
    q.x = (i8)(int)fminf(1.f, fmaxf(-1.f, rintf(v[0] * inv)));
    q.y = (i8)(int)fminf(1.f, fmaxf(-1.f, rintf(v[1] * inv)));
    q.z = (i8)(int)fminf(1.f, fmaxf(-1.f, rintf(v[2] * inv)));
    q.w = (i8)(int)fminf(1.f, fmaxf(-1.f, rintf(v[3] * inv)));
    ((char4*)wq)[i] = q;
  }
}

// ------- 3) i8 GEMM: 4 waves x (128x128), all-fragments-first tile body -------
// R6 (45.5us, best) with ONE structural change: all 32 fragment ds_reads are
// hoisted to the top of the tile body, then the 16 GLDS, then 4 back-to-back
// MFMA clusters. At 1 wave/SIMD (acc[4][4]=256 AGPR forces it) the only
// latency hiding is in-wave ILP: one wave's 32 reads need ~400 CU-cyc of LDS
// pipe vs the 2342-cyc MFMA window -- issued up front, the compiler's counted
// lgkmcnt lets MFMA start when the first fragments land while the rest of the
// reads + DMA drain underneath. setprio kept (present in the 45.5 baseline).
// Bank-conflict counter (= exactly 4.0/read in R3/R6/R8) is the deterministic
// cost of row-scattered b128 reads; the lane-linear alternative costs more in
// scattered GLDS (R4: +22us). Accepted as floor tax.
#define GLDS(SRC, DST) __builtin_amdgcn_global_load_lds( \
    (const __attribute__((address_space(1))) void*)(SRC), \
    (__attribute__((address_space(3))) void*)(DST), 16, 0, 0)
#define WAITVM(N) asm volatile("s_waitcnt vmcnt(" #N ")")
#define BAR()     __builtin_amdgcn_s_barrier()
#define FENCE()   __builtin_amdgcn_sched_barrier(0)

__global__ __launch_bounds__(256, 1) void gemm_bt(const i8* __restrict__ A,
                                                  const i8* __restrict__ Bw,
                                                  const float* __restrict__ gamma_p,
                                                  const float* __restrict__ srow,
                                                  float* __restrict__ C) {
  extern __shared__ i8 lds[];   // slot s: A at s*65536, B at s*65536+32768

  int f   = blockIdx.y * 8 + blockIdx.x;   // 0..255, x-fastest
  int xcd = f & 7;
  int gg  = f >> 3;
  int orig = xcd * 32 + gg;
  int nb  = orig & 7;
  int mb  = orig >> 3;
  int bm0 = mb * BM;
  int bn0 = nb * BN;

  int tid  = threadIdx.x;
  int lane = tid & 63;
  int wv   = tid >> 6;          // 0..3
  int wr   = wv >> 1;           // 0..1 -> rows wr*128
  int wc   = wv & 1;            // 0..1 -> cols wc*128
  int l31  = lane & 31;
  int hi   = lane >> 5;

  const i8* Ag = A  + (size_t)bm0 * D_INNER;
  const i8* Bg = Bw + (size_t)bn0 * D_INNER;

  // staging decode (verified R3/R6): round rr covers rows rr*32+(tid>>3);
  // src chunk XOR'd by row&7 (== (tid>>3)&7); dst linear rr*4096 + tid*16.
  size_t srcx = (size_t)(tid >> 3) * D_INNER + (((tid & 7) ^ ((tid >> 3) & 7)) << 4);

  // read addressing (verified)
  int rdA = (wr * 128 + l31) * BK;            // + mi*4096 + swz[ks]
  int rdB = 32768 + (wc * 128 + l31) * BK;    // + nj*4096 + swz[ks]
  int swz[4];
#pragma unroll
  for (int ks = 0; ks < 4; ++ks)
    swz[ks] = (((ks << 1) | hi) ^ (l31 & 7)) << 4;

  i32x16 acc[4][4] = {};

#define GLDS_A(T_, RR, S_) \
    GLDS(Ag + srcx + (size_t)(RR) * (32 * D_INNER) + (size_t)(T_) * BK, \
         lds + (S_) * SLOT_BYTES + (RR) * 4096 + tid * 16)
#define GLDS_B(T_, RR, S_) \
    GLDS(Bg + srcx + (size_t)(RR) * (32 * D_INNER) + (size_t)(T_) * BK, \
         lds + (S_) * SLOT_BYTES + 32768 + (RR) * 4096 + tid * 16)

#define TILE(T_, DS_) do { \
    WAITVM(0);               /* tile T_'s 16 loads landed (t+1 not issued) */ \
    FENCE(); \
    BAR();                   /* publish across waves; slot (T_+1)&1 free */ \
    FENCE(); \
    const i8* sl_ = lds + ((T_) & 1) * SLOT_BYTES; \
    i32x4 bf_[4][4]; \
    _Pragma("unroll") for (int ks = 0; ks < 4; ++ks) \
      _Pragma("unroll") for (int nj = 0; nj < 4; ++nj) \
        bf_[ks][nj] = *(const i32x4*)(sl_ + rdB + nj * 4096 + swz[ks]); \
    i32x4 af_[4][4]; \
    _Pragma("unroll") for (int mi = 0; mi < 4; ++mi) \
      _Pragma("unroll") for (int ks = 0; ks < 4; ++ks) \
        af_[mi][ks] = *(const i32x4*)(sl_ + rdA + mi * 4096 + swz[ks]); \
    if (DS_) { \
      _Pragma("unroll") for (int rr = 0; rr < 8; ++rr) { \
        GLDS_A((T_) + 1, rr, ((T_) + 1) & 1); \
        GLDS_B((T_) + 1, rr, ((T_) + 1) & 1); \
      } \
    } \
    _Pragma("unroll") for (int mi = 0; mi < 4; ++mi) { \
      __builtin_amdgcn_s_setprio(1); \
      _Pragma("unroll") for (int ks = 0; ks < 4; ++ks) \
        _Pragma("unroll") for (int nj = 0; nj < 4; ++nj) \
          acc[mi][nj] = __builtin_amdgcn_mfma_i32_32x32x32_i8( \
              af_[mi][ks], bf_[ks][nj], acc[mi][nj], 0, 0, 0); \
      __builtin_amdgcn_s_setprio(0); \
    } \
  } while (0)

  // prologue: full tile 0 into slot 0
#pragma unroll
  for (int rr = 0; rr < 8; ++rr) { GLDS_A(0, rr, 0); GLDS_B(0, rr, 0); }

  for (int t = 0; t < NKT - 1; ++t)
    TILE(t, 1);
  TILE(NKT - 1, 0);

  // epilogue: C/D 32x32 layout: col = lane&31, row = (reg&3) + 8*(reg>>2) + 4*hi
  // nontemporal stores: C is write-once, never re-read -> skip L2 allocate.
  float gamma = *gamma_p;
#pragma unroll
  for (int mi = 0; mi < 4; ++mi) {
    int rbase = bm0 + wr * 128 + mi * 32 + hi * 4;
    f32x4 sg[4];
#pragma unroll
    for (int q = 0; q < 4; ++q) {
      f32x4 sv = *(const f32x4*)(srow + rbase + q * 8);
      sg[q] = sv * gamma;
    }
#pragma unroll
    for (int nj = 0; nj < 4; ++nj) {
      int colb = bn0 + wc * 128 + nj * 32 + l31;
      i32x16 v = acc[mi][nj];
      float* cp = C + (size_t)rbase * D_OUTER + colb;
#pragma unroll
      for (int q = 0; q < 4; ++q)
#pragma unroll
        for (int rr = 0; rr < 4; ++rr)
          __builtin_nontemporal_store((float)v[q * 4 + rr] * sg[q][rr],
                                      &cp[(size_t)(q * 8 + rr) * D_OUTER]);
    }
  }
}

extern "C" void kernel_launch(void* const* d_in, const int* in_sizes, int n_in,
                              void* d_out, int out_size, void* d_ws, size_t ws_size,
                              hipStream_t stream) {
  const float* x = (const float*)d_in[0];   // [2,4096,2048]
  const float* w = (const float*)d_in[1];   // [2048,2048]
  const float* g = (const float*)d_in[2];   // [2048]
  float* out = (float*)d_out;               // [2,4096,2048] fp32

  float* gamma_p  = (float*)d_ws;                                  // 1 float
  float* partials = (float*)((char*)d_ws + 64);                    // 1024 floats
  float* srow     = (float*)((char*)d_ws + 8192);                  // 8192 floats
  i8* xn = (i8*)((char*)d_ws + 8192 + 32768);                      // 16 MB
  i8* wq = (i8*)((char*)d_ws + 8192 + 32768 + (size_t)MROWS * D_INNER);  // 4 MB

  static bool attr_set = false;
  if (!attr_set) {
    (void)hipFuncSetAttribute(reinterpret_cast<const void*>(&gemm_bt),
                              hipFuncAttributeMaxDynamicSharedMemorySize, LDS_TOTAL);
    attr_set = true;
  }

  prep_kernel<<<MROWS / 4 + NPART, 256, 0, stream>>>(x, g, w, xn, srow, partials);
  quant_kernel<<<2048, 256, 0, stream>>>(w, partials, gamma_p, wq);
  gemm_bt<<<dim3(8, 32), 256, LDS_TOTAL, stream>>>(xn, wq, gamma_p, srow, out);
}

// Round 10
// 162.592 us; speedup vs baseline: 1.0293x; 1.0210x over previous
//
#include <hip/hip_runtime.h>
#include <hip/hip_bf16.h>
#include <stdint.h>

typedef unsigned short u16;
typedef signed char i8;

#define D_INNER 2048
#define D_OUTER 2048
#define MROWS   8192                 // B*S = 2*4096
#define W_ELEMS (D_OUTER * D_INNER)  // 4194304
#define NPART   1024                 // absmean partial blocks

// ---- gemm geometry: m201-style 8-phase, 256x256 tile, BK=128 i8 (R3 = best) ----
#define BM 256
#define BN 256
#define BK 128
#define NKT (D_INNER / BK)           // 16 K-tiles, 2 per iter, 8 iters
#define SLOT_BYTES 65536             // A 32KB + B 32KB per slot
#define LDS_TOTAL  131072            // 2 slots

typedef __attribute__((ext_vector_type(4))) float f32x4;
typedef __attribute__((ext_vector_type(4))) int   i32x4;
typedef __attribute__((ext_vector_type(16))) int  i32x16;

// ------- 1) prep (R5/R6 verified): RMSNorm one wave/row + |w| partials -------
__global__ __launch_bounds__(256) void prep_kernel(const float* __restrict__ x,
                            const float* __restrict__ g,
                            const float* __restrict__ w,
                            i8* __restrict__ xn, float* __restrict__ srow,
                            float* __restrict__ partials) {
  int t = threadIdx.x;
  int lane = t & 63, wvi = t >> 6;

  if (blockIdx.x >= MROWS / 4) {
    __shared__ float red[4];
    int p = blockIdx.x - MROWS / 4;
    int base = p * 1024;
    float s = 0.f;
#pragma unroll
    for (int r = 0; r < 4; ++r) {
      f32x4 v = ((const f32x4*)w)[base + r * 256 + t];
      s += fabsf(v[0]) + fabsf(v[1]) + fabsf(v[2]) + fabsf(v[3]);
    }
    for (int off = 32; off; off >>= 1) s += __shfl_down(s, off, 64);
    if (lane == 0) red[wvi] = s;
    __syncthreads();
    if (t == 0) partials[p] = red[0] + red[1] + red[2] + red[3];
    return;
  }

  int row = blockIdx.x * 4 + wvi;
  const f32x4* xr = (const f32x4*)(x + (size_t)row * D_INNER);
  const f32x4* gr = (const f32x4*)g;
  i8* xo = xn + (size_t)row * D_INNER;

  f32x4 v[8], gv[8];
#pragma unroll
  for (int r = 0; r < 8; ++r) {
    v[r]  = __builtin_nontemporal_load(&xr[lane + r * 64]);
    gv[r] = gr[lane + r * 64];
  }
  float s = 0.f, m = 0.f;
#pragma unroll
  for (int r = 0; r < 8; ++r) {
    s += v[r][0]*v[r][0] + v[r][1]*v[r][1] + v[r][2]*v[r][2] + v[r][3]*v[r][3];
    m = fmaxf(m, fmaxf(fmaxf(fabsf(v[r][0]*gv[r][0]), fabsf(v[r][1]*gv[r][1])),
                       fmaxf(fabsf(v[r][2]*gv[r][2]), fabsf(v[r][3]*gv[r][3]))));
  }
#pragma unroll
  for (int off = 32; off; off >>= 1) {
    s += __shfl_xor(s, off, 64);
    m = fmaxf(m, __shfl_xor(m, off, 64));
  }
  float invr = 1.0f / sqrtf(s * (1.0f / (float)D_INNER) + 1e-6f);
  float amax = fmaxf(m * invr, 1e-12f);
  float step = amax * (1.0f / 127.0f);
  float qs   = 127.0f / amax;
  if (lane == 0) srow[row] = step;

#pragma unroll
  for (int r = 0; r < 8; ++r) {
    char4 q;
    float qv;
    qv = fminf(127.f, fmaxf(-127.f, rintf(v[r][0]*invr*gv[r][0]*qs))); q.x = (i8)(int)qv;
    qv = fminf(127.f, fmaxf(-127.f, rintf(v[r][1]*invr*gv[r][1]*qs))); q.y = (i8)(int)qv;
    qv = fminf(127.f, fmaxf(-127.f, rintf(v[r][2]*invr*gv[r][2]*qs))); q.z = (i8)(int)qv;
    qv = fminf(127.f, fmaxf(-127.f, rintf(v[r][3]*invr*gv[r][3]*qs))); q.w = (i8)(int)qv;
    ((char4*)xo)[lane + r * 64] = q;
  }
}

// ------- 2) ternary quantize (FROZEN) -------
__global__ __launch_bounds__(256) void quant_kernel(const float* __restrict__ w,
                             const float* __restrict__ partials,
                             float* __restrict__ gamma_out, i8* __restrict__ wq) {
  f32x4 pv = ((const f32x4*)partials)[threadIdx.x];
  double d = (double)pv[0] + (double)pv[1] + (double)pv[2] + (double)pv[3];
  for (int off = 32; off; off >>= 1) d += __shfl_down(d, off, 64);
  __shared__ double red[4];
  int lane = threadIdx.x & 63, wvi = threadIdx.x >> 6;
  if (lane == 0) red[wvi] = d;
  __syncthreads();
  double total = red[0] + red[1] + red[2] + red[3];
  float gamma = (float)(total * (1.0 / (double)W_ELEMS));
  float inv = 1.0f / (gamma + 1e-8f);
  if (blockIdx.x == 0 && threadIdx.x == 0) *gamma_out = gamma;

  int tid = blockIdx.x * blockDim.x + threadIdx.x;
  int stride = gridDim.x * blockDim.x;
  for (int i = tid; i < W_ELEMS / 4; i += stride) {
    f32x4 v = ((const f32x4*)w)[i];
    char4 q;
    q.x = (i8)(int)fminf(1.f, fmaxf(-1.f, rintf(v[0] * inv)));
    q.y = (i8)(int)fminf(1.f, fmaxf(-1.f, rintf(v[1] * inv)));
    q.z = (i8)(int)fminf(1.f, fmaxf(-1.f, rintf(v[2] * inv)));
    q.w = (i8)(int)fminf(1.f, fmaxf(-1.f, rintf(v[3] * inv)));
    ((char4*)wq)[i] = q;
  }
}

// ------- 3) i8 GEMM: R3's 8-phase schedule VERBATIM (session best, 43.2us) ----
// Only delta vs R3: nontemporal C stores (write-once output; frees L2 for the
// A/B/xn streams). All schedule/addressing bytes identical to the verified R3.
#define GLDS(SRC, DST) __builtin_amdgcn_global_load_lds( \
    (const __attribute__((address_space(1))) void*)(SRC), \
    (__attribute__((address_space(3))) void*)(DST), 16, 0, 0)
#define WAITVM(N) asm volatile("s_waitcnt vmcnt(" #N ")")
#define BAR()     __builtin_amdgcn_s_barrier()
#define FENCE()   __builtin_amdgcn_sched_barrier(0)
#define LGKM0()   do { asm volatile("s_waitcnt lgkmcnt(0)"); FENCE(); } while (0)

__global__ __launch_bounds__(512, 2) void gemm_bt(const i8* __restrict__ A,
                                                  const i8* __restrict__ Bw,
                                                  const float* __restrict__ gamma_p,
                                                  const float* __restrict__ srow,
                                                  float* __restrict__ C) {
  extern __shared__ i8 lds[];   // slot s: A at s*65536, B at s*65536+32768

  int f   = blockIdx.y * 8 + blockIdx.x;   // 0..255, x-fastest
  int xcd = f & 7;
  int gg  = f >> 3;
  int orig = xcd * 32 + gg;
  int nb  = orig & 7;
  int mb  = orig >> 3;
  int bm0 = mb * BM;
  int bn0 = nb * BN;

  int tid  = threadIdx.x;
  int lane = tid & 63;
  int wv   = tid >> 6;          // 0..7
  int wr   = wv >> 2;           // 0..1 -> rows wr*128
  int wc   = wv & 3;            // 0..3 -> cols wc*64
  int l31  = lane & 31;
  int hi   = lane >> 5;

  const i8* Ag = A  + (size_t)bm0 * D_INNER;
  const i8* Bg = Bw + (size_t)bn0 * D_INNER;

  // staging decode: A-part P = rows {P*32..+32} u {128+P*32..+32} (8KB);
  // B-part P = rows {P*64..+64} (8KB). Dest linear in tid; src XOR-permuted.
  int s_arow = (tid >> 8) * 128 + ((tid & 255) >> 3);   // + P*32
  int s_adst = (tid >> 8) * 16384 + (tid & 255) * 16;   // + P*4096 (+slot)
  int s_brow = tid >> 3;                                // + P*64
  int s_chunk = tid & 7;

  // read addressing
  int rbyteA = (wr * 128 + l31) * 128;                  // + tph*4096 + swz
  int rbyteB[2];
  rbyteB[0] = (wc * 64 + l31) * 128;
  rbyteB[1] = (wc * 64 + 32 + l31) * 128;
  int swz[4];
#pragma unroll
  for (int ks = 0; ks < 4; ++ks)
    swz[ks] = (((ks << 1) | hi) ^ (l31 & 7)) << 4;

  i32x16 acc[4][2] = {};
  i32x4 bfr[4][2];

#define STAGE_AB(T_, P_, S_) do { \
    int ar_ = (P_) * 32 + s_arow; \
    GLDS(Ag + (size_t)ar_ * D_INNER + (T_) * BK + ((s_chunk ^ (ar_ & 7)) << 4), \
         lds + (S_) * SLOT_BYTES + (P_) * 4096 + s_adst); \
    int br_ = (P_) * 64 + s_brow; \
    GLDS(Bg + (size_t)br_ * D_INNER + (T_) * BK + ((s_chunk ^ (br_ & 7)) << 4), \
         lds + (S_) * SLOT_BYTES + 32768 + (P_) * 8192 + tid * 16); \
  } while (0)

#define MFMA8(TPH) do { \
    __builtin_amdgcn_s_setprio(1); \
    _Pragma("unroll") for (int ks = 0; ks < 4; ++ks) \
      _Pragma("unroll") for (int nj = 0; nj < 2; ++nj) \
        acc[(TPH)][nj] = __builtin_amdgcn_mfma_i32_32x32x32_i8( \
            af_[ks], bfr[ks][nj], acc[(TPH)][nj], 0, 0, 0); \
    __builtin_amdgcn_s_setprio(0); \
  } while (0)

// tile-phase 0 (PP = 0 or 4): publish tile (wait+bar) BEFORE its reads.
#define PHASE0(IT, PP, WAITSTMT, DS_) do { \
    if (DS_) { int T_ = ((PP) == 0) ? (2 * (IT) + 1) : (2 * (IT) + 2 + ((((PP)-1) & 7) >> 2)); \
               STAGE_AB(T_, (((PP)-1) & 3), ((((PP)-1) & 7) >> 2)); } \
    WAITSTMT; \
    BAR(); \
    const i8* sb_ = lds + ((PP) >> 2) * SLOT_BYTES; \
    i32x4 af_[4]; \
    _Pragma("unroll") for (int ks = 0; ks < 4; ++ks) \
      af_[ks] = *(const i32x4*)(sb_ + rbyteA + swz[ks]); \
    _Pragma("unroll") for (int ks = 0; ks < 4; ++ks) \
      _Pragma("unroll") for (int nj = 0; nj < 2; ++nj) \
        bfr[ks][nj] = *(const i32x4*)(sb_ + 32768 + rbyteB[nj] + swz[ks]); \
    LGKM0(); \
    MFMA8(0); \
    BAR(); \
  } while (0)

// tile-phases 1..3: reads pre-barrier (data published at tile start).
#define PHASEK(IT, PP, DS_) do { \
    const i8* sb_ = lds + ((PP) >> 2) * SLOT_BYTES; \
    i32x4 af_[4]; \
    _Pragma("unroll") for (int ks = 0; ks < 4; ++ks) \
      af_[ks] = *(const i32x4*)(sb_ + rbyteA + ((PP) & 3) * 4096 + swz[ks]); \
    if (DS_) { int T_ = 2 * (IT) + 2 + ((((PP)-1) & 7) >> 2); \
               STAGE_AB(T_, (((PP)-1) & 3), ((((PP)-1) & 7) >> 2)); } \
    BAR(); \
    LGKM0(); \
    MFMA8((PP) & 3); \
    BAR(); \
  } while (0)

  // prologue: tile0 fully + tile1 parts 0-2 (14 loads/thread)
  STAGE_AB(0, 0, 0); STAGE_AB(0, 1, 0); STAGE_AB(0, 2, 0); STAGE_AB(0, 3, 0);
  STAGE_AB(1, 0, 1); STAGE_AB(1, 1, 1); STAGE_AB(1, 2, 1);

  for (int it = 0; it < 7; ++it) {
    PHASE0(it, 0, WAITVM(8), 1);
    PHASEK(it, 1, 1);
    PHASEK(it, 2, 1);
    PHASEK(it, 3, 1);
    PHASE0(it, 4, WAITVM(8), 1);
    PHASEK(it, 5, 1);
    PHASEK(it, 6, 1);
    PHASEK(it, 7, 1);
  }
  // peeled it=7: only the p=0 stage (tile 15 part 3) remains in-range
  PHASE0(7, 0, WAITVM(8), 1);
  PHASEK(7, 1, 0);
  PHASEK(7, 2, 0);
  PHASEK(7, 3, 0);
  PHASE0(7, 4, WAITVM(0), 0);
  PHASEK(7, 5, 0);
  PHASEK(7, 6, 0);
  PHASEK(7, 7, 0);

  // epilogue: C/D 32x32 layout: col = lane&31, row = (reg&3) + 8*(reg>>2) + 4*hi
  // nontemporal: C is write-once, never re-read.
  float gamma = *gamma_p;
  int colb = bn0 + wc * 64 + l31;
#pragma unroll
  for (int mi = 0; mi < 4; ++mi) {
    int rbase = bm0 + wr * 128 + mi * 32 + hi * 4;
    f32x4 sg[4];
#pragma unroll
    for (int q = 0; q < 4; ++q) {
      f32x4 sv = *(const f32x4*)(srow + rbase + q * 8);
      sg[q] = sv * gamma;
    }
#pragma unroll
    for (int nj = 0; nj < 2; ++nj) {
      i32x16 v = acc[mi][nj];
      float* cp = C + (size_t)rbase * D_OUTER + (colb + nj * 32);
#pragma unroll
      for (int q = 0; q < 4; ++q)
#pragma unroll
        for (int rr = 0; rr < 4; ++rr)
          __builtin_nontemporal_store((float)v[q * 4 + rr] * sg[q][rr],
                                      &cp[(size_t)(q * 8 + rr) * D_OUTER]);
    }
  }
}

extern "C" void kernel_launch(void* const* d_in, const int* in_sizes, int n_in,
                              void* d_out, int out_size, void* d_ws, size_t ws_size,
                              hipStream_t stream) {
  const float* x = (const float*)d_in[0];   // [2,4096,2048]
  const float* w = (const float*)d_in[1];   // [2048,2048]
  const float* g = (const float*)d_in[2];   // [2048]
  float* out = (float*)d_out;               // [2,4096,2048] fp32

  float* gamma_p  = (float*)d_ws;                                  // 1 float
  float* partials = (float*)((char*)d_ws + 64);                    // 1024 floats
  float* srow     = (float*)((char*)d_ws + 8192);                  // 8192 floats
  i8* xn = (i8*)((char*)d_ws + 8192 + 32768);                      // 16 MB
  i8* wq = (i8*)((char*)d_ws + 8192 + 32768 + (size_t)MROWS * D_INNER);  // 4 MB

  static bool attr_set = false;
  if (!attr_set) {
    (void)hipFuncSetAttribute(reinterpret_cast<const void*>(&gemm_bt),
                              hipFuncAttributeMaxDynamicSharedMemorySize, LDS_TOTAL);
    attr_set = true;
  }

  prep_kernel<<<MROWS / 4 + NPART, 256, 0, stream>>>(x, g, w, xn, srow, partials);
  quant_kernel<<<2048, 256, 0, stream>>>(w, partials, gamma_p, wq);
  gemm_bt<<<dim3(8, 32), 512, LDS_TOTAL, stream>>>(xn, wq, gamma_p, srow, out);
}